// Round 16
// baseline (114.763 us; speedup 1.0000x reference)
//
#include <hip/hip_runtime.h>
#include <hip/hip_bf16.h>

#define NFFT   4194304
#define NMODES 2
#define NTAPS  101
#define NVALID (NFFT - NTAPS + 1)   // 4194204
#define N0     (NTAPS / 2)          // 50

constexpr int BLOCK = 256;                          // 4 waves
constexpr int TILE  = 2048;                         // output samples per block
constexpr int NT    = (NVALID + TILE - 1) / TILE;   // 2048 blocks
constexpr int WIN   = 2176;                         // staged P samples (max read idx 2151)
constexpr int NM    = 15;                           // banded MFMA accumulation steps
constexpr int TWRD  = 136;                          // words per rotated B table
constexpr int NTAB  = 8;                            // tables: r(4) x o(2)

// LDS word layout: xaR[0..4351] | xbR[4352..8703] | Pl[8704..10879] | Bt[10880..11967]
constexpr int OXB = 4352;
constexpr int OPL = 8704;
constexpr int OBT = 10880;
constexpr int LWORDS = 11968;                       // 47872 B -> 3 blocks/CU

typedef __attribute__((ext_vector_type(8)))  short short8;
typedef __attribute__((ext_vector_type(16))) float float16;

static __device__ __forceinline__ unsigned short f2bf(float x) {
    __hip_bfloat16 h = __float2bfloat16(x);
    return *reinterpret_cast<unsigned short*>(&h);
}
static __device__ __forceinline__ unsigned pk(float e0, float e1) {
    return (unsigned)f2bf(e0) | ((unsigned)f2bf(e1) << 16);
}
// XOR word bits 2..4 with word bits 5..7: bijective, preserves aligned 4-word groups,
// spreads 64B-stride accesses across banks (residual 2-way = free).
static __device__ __forceinline__ int swz(int s) {
    return s ^ (((s >> 5) & 7) << 2);
}
// HBM -> LDS direct (16B/lane, no VGPR round trip). LDS dest must be linear:
// lane's pointer == wave-uniform base + lane*16 (holds for c = uniform + lane).
static __device__ __forceinline__ void gl16(const float4* g, unsigned* l) {
    __builtin_amdgcn_global_load_lds(
        (const __attribute__((address_space(1))) void*)g,
        (__attribute__((address_space(3))) void*)l, 16, 0, 0);
}

__global__ __launch_bounds__(BLOCK, 3) void nl_kernel(
    const float* __restrict__ xa,   // d_in[0] big stream (A = xr)
    const float* __restrict__ xb,   // d_in[1] big stream (B = xi)
    const float* __restrict__ W,  const float* __restrict__ b,
    const float* __restrict__ power, unsigned* __restrict__ out)
{
    __shared__ __align__(16) unsigned lds[LWORDS];
    unsigned* const xaR = lds;
    unsigned* const xbR = lds + OXB;
    unsigned* const Pl  = lds + OPL;
    unsigned* const Bt  = lds + OBT;

    const int tid  = threadIdx.x;
    const int lane = tid & 63;
    const int wid  = tid >> 6;
    const int colc = lane & 31;      // B/C column = (c_s<<1)|o ; also A row index
    const int h    = lane >> 5;      // k half: k = 8h + e
    const int cs   = colc >> 1;      // fine shift 0..15
    const int o    = colc & 1;       // output mode
    const int r    = colc;           // A row

    const int tile_start = blockIdx.x * TILE;
    const int ts2        = tile_start >> 1;
    const bool full      = (blockIdx.x != NT - 1);

    const float4* __restrict__ xa4 = reinterpret_cast<const float4*>(xa); // 2 samples
    const float4* __restrict__ xb4 = reinterpret_cast<const float4*>(xb);

    // ---- 0) rotated B tables FIRST (their W loads retire before staging issues,
    //         keeping the stage vmcnt arithmetic exact).
    // Bt[(2r+o)*136 + 4q + d] = Bval(tau = 4q + r + d, o), Bval(tau,o) =
    // pk(W[tau-15,0,o], W[tau-15,1,o]) for tau-15 in [0,100], else 0. Gives each
    // lane one aligned ds_read_b128 per m (tau0 & 3 is m-invariant since 8m%4==0).
    {
        const float4* __restrict__ Wt = reinterpret_cast<const float4*>(W);
        for (int idx = tid; idx < NTAB * TWRD; idx += BLOCK) {
            const int tab = idx / TWRD;
            const int w   = idx - tab * TWRD;
            const int rr  = tab >> 1, oo = tab & 1;
            const int t   = (w & ~3) + rr + (w & 3) - 15;   // tau - 15
            const bool ok = (unsigned)t <= 100u;
            const float4 ww = Wt[ok ? t : 0];
            Bt[idx] = ok ? pk(oo ? ww.y : ww.x, oo ? ww.w : ww.z) : 0u;
        }
    }
    __builtin_amdgcn_sched_barrier(0);

    // ---- 1) issue ALL stage DMA: 5 pairs/thread, uniform (pair 4 is a benign
    //         4-way duplicate of chunks 1024..1087 -> same addr, same data) ----
    // Chunk c staged by thread tid and P-read ONLY by thread tid.
    #pragma unroll
    for (int k = 0; k < 5; ++k) {
        const int c  = (k < 4) ? (tid + 256 * k) : (1024 + (tid & 63));
        const int cc = min(ts2 + c, NFFT / 2 - 1);   // clamp OOB (zeroed in P-compute)
        gl16(xa4 + cc, &xaR[4 * c]);                 // op 2k
        gl16(xb4 + cc, &xbR[4 * c]);                 // op 2k+1
    }

    // ---- 2) consume pair-by-pair with counted vmcnt: P-compute of pair k needs
    //         only ops 0..2k+1 retired -> wait vmcnt(8-2k). Later loads stay in
    //         flight under the earlier pairs' compute (no full drain). ----
    #define PSTEP(K, CNT, GUARDED) {                                                \
        asm volatile("s_waitcnt vmcnt(" CNT ")" ::: "memory");                      \
        __builtin_amdgcn_sched_barrier(0);                                          \
        const int tp = ((K) < 4) ? (tid + 256 * (K)) : (1024 + (tid & 63));         \
        const float4 a = *reinterpret_cast<const float4*>(&xaR[4 * tp]);            \
        const float4 c = *reinterpret_cast<const float4*>(&xbR[4 * tp]);            \
        unsigned u0, u1;                                                            \
        if (GUARDED) {                                                              \
            const int g = tile_start + 2 * tp;       /* even; g,g+1 together */     \
            u0 = u1 = 0u;                                                           \
            if (g < NFFT) {                                                         \
                u0 = pk(a.x * a.x + c.x * c.x, a.y * a.y + c.y * c.y);              \
                u1 = pk(a.z * a.z + c.z * c.z, a.w * a.w + c.w * c.w);              \
            }                                                                       \
        } else {                                                                    \
            u0 = pk(a.x * a.x + c.x * c.x, a.y * a.y + c.y * c.y);                  \
            u1 = pk(a.z * a.z + c.z * c.z, a.w * a.w + c.w * c.w);                  \
        }                                                                           \
        *reinterpret_cast<uint2*>(&Pl[swz(2 * tp)]) = make_uint2(u0, u1);           \
    }
    if (full) {          // full tile: no NFFT guard in the hot path
        PSTEP(0, "8", false)
        PSTEP(1, "6", false)
        PSTEP(2, "4", false)
        PSTEP(3, "2", false)
        PSTEP(4, "0", false)
    } else {             // last block: guarded
        PSTEP(0, "8", true)
        PSTEP(1, "6", true)
        PSTEP(2, "4", true)
        PSTEP(3, "2", true)
        PSTEP(4, "0", true)
    }
    #undef PSTEP

    __syncthreads();     // vmcnt already 0; makes Pl/Bt/raw visible block-wide

    // ---- 3) per-wave 512-sample chunk: 15 x (b128 A + b128 B + MFMA) ----
    const int cb   = wid * 512;
    const int tau0 = 4 * h - cs + 15;                 // in [0,19]
    const int tb   = (((tau0 & 3) << 1) | o) * TWRD + (tau0 >> 2) * 4;
    float16 acc = {};
    uint4 areg[4];                    // 4-deep A prefetch pipe (static idx post-unroll)
    #pragma unroll
    for (int m = 0; m < 4; ++m)
        areg[m] = *reinterpret_cast<const uint4*>(&Pl[swz(cb + 16 * r + 8 * m + 4 * h)]);
    #pragma unroll
    for (int m = 0; m < NM; ++m) {
        const uint4 bq = *reinterpret_cast<const uint4*>(&Bt[tb + 8 * m]);
        acc = __builtin_amdgcn_mfma_f32_32x32x16_bf16(
                  __builtin_bit_cast(short8, areg[m & 3]),
                  __builtin_bit_cast(short8, bq), acc, 0, 0, 0);
        if (m + 4 < NM)
            areg[m & 3] = *reinterpret_cast<const uint4*>(
                              &Pl[swz(cb + 16 * r + 8 * (m + 4) + 4 * h)]);
    }

    // ---- 4) epilogue: direct from accumulators; x re-read from LDS raw copy ----
    // C/D: col = lane&31, row = (reg&3) + 8*(reg>>2) + 4*(lane>>5).
    // local x word = 2*(cb + 16*row + cs + N0) + o, max 4195 < 4352: always staged.
    const float bo   = o ? b[1] : b[0];
    const float coef = 0.066268f * exp10f(power[0] * 0.1f);
    const float* __restrict__ xaF = reinterpret_cast<const float*>(xaR);
    const float* __restrict__ xbF = reinterpret_cast<const float*>(xbR);

    if (full) {                                       // full tile: branch-free
        #pragma unroll
        for (int j = 0; j < 16; ++j) {
            const int row = (j & 3) + 8 * (j >> 2) + 4 * h;
            const int lw  = 2 * (cb + 16 * row + cs + N0) + o;
            const float Ax = xaF[lw];
            const float Bx = xbF[lw];
            float sn, cn;
            __sincosf((acc[j] + bo) * coef, &sn, &cn);
            const int n = tile_start + cb + 16 * row + cs;
            __builtin_nontemporal_store(pk(Bx * cn - Ax * sn, Ax * cn + Bx * sn),
                                        &out[n * 2 + o]);
        }
    } else {                                          // tail tile: guarded stores
        #pragma unroll
        for (int j = 0; j < 16; ++j) {
            const int row = (j & 3) + 8 * (j >> 2) + 4 * h;
            const int n   = tile_start + cb + 16 * row + cs;
            if (n < NVALID) {
                const int lw  = 2 * (cb + 16 * row + cs + N0) + o;
                const float Ax = xaF[lw];
                const float Bx = xbF[lw];
                float sn, cn;
                __sincosf((acc[j] + bo) * coef, &sn, &cn);
                __builtin_nontemporal_store(pk(Bx * cn - Ax * sn, Ax * cn + Bx * sn),
                                            &out[n * 2 + o]);
            }
        }
    }
}

extern "C" void kernel_launch(void* const* d_in, const int* in_sizes, int n_in,
                              void* d_out, int out_size, void* d_ws, size_t ws_size,
                              hipStream_t stream) {
    // Bind by size (robust): big arrays = x streams, 404 = W, 2 = b, 1 = power.
    const float* big[2] = {nullptr, nullptr};
    const float* W = nullptr; const float* b = nullptr; const float* power = nullptr;
    int nbig = 0;
    for (int i = 0; i < n_in; ++i) {
        const float* p = (const float*)d_in[i];
        const int sz = in_sizes[i];
        if (sz == NFFT * NMODES)       { if (nbig < 2) big[nbig++] = p; }
        else if (sz == NTAPS * NMODES * NMODES) { W = p; }
        else if (sz == NMODES)         { b = p; }
        else if (sz == 1)              { power = p; }
    }

    unsigned* out = (unsigned*)d_out;
    nl_kernel<<<NT, BLOCK, 0, stream>>>(big[0], big[1], W, b, power, out);
}